// Round 7
// baseline (239.260 us; speedup 1.0000x reference)
//
#include <hip/hip_runtime.h>
#include <stdint.h>

typedef unsigned short ushort_t;

#define T_SEQ 2048
#define BATCH 4
#define NHEAD 12
#define CEMB 768
#define HDIM 64
#define C3 2304

// ---------- bf16 helpers (HW convert, RNE) ----------
__device__ __forceinline__ ushort_t f2b_hw(float f) {
  union { __bf16 h; ushort_t u; } p;
  p.h = (__bf16)f;
  return p.u;
}
__device__ __forceinline__ uint32_t pkbf16(float lo, float hi) {
  union { __bf16 h[2]; uint32_t u; } p;
  p.h[0] = (__bf16)lo; p.h[1] = (__bf16)hi;
  return p.u;
}

// ---------- async global->LDS 16B ----------
typedef __attribute__((address_space(3))) unsigned int lds_u32_t;
typedef const __attribute__((address_space(1))) unsigned int glb_u32_t;
__device__ __forceinline__ void async_cp16(const void* g, void* l) {
  __builtin_amdgcn_global_load_lds((glb_u32_t*)g, (lds_u32_t*)l, 16, 0, 0);
}

// ---------- fused prep: cvt x -> bf16; transpose+cvt both weights ----------
__global__ __launch_bounds__(256) void prep_k(const float* __restrict__ x, ushort_t* __restrict__ xb,
                                              const float* __restrict__ wa, ushort_t* __restrict__ wT,
                                              const float* __restrict__ wp, ushort_t* __restrict__ wpT) {
  const int blk = blockIdx.x;
  const int tid = threadIdx.x;
  if (blk < 3072) {
    const int i = blk * 256 + tid;
    float4 a = ((const float4*)x)[2 * i];
    float4 b = ((const float4*)x)[2 * i + 1];
    uint4 v;
    v.x = pkbf16(a.x, a.y); v.y = pkbf16(a.z, a.w);
    v.z = pkbf16(b.x, b.y); v.w = pkbf16(b.z, b.w);
    ((uint4*)xb)[i] = v;
    return;
  }
  __shared__ ushort_t tile[32][33];
  const float* in; ushort_t* out; int R, C, bx, by;
  if (blk < 4800) {
    const int t = blk - 3072;
    in = wa; out = wT; R = CEMB; C = C3;
    bx = t % 72; by = t / 72;
  } else {
    const int t = blk - 4800;
    in = wp; out = wpT; R = CEMB; C = CEMB;
    bx = t % 24; by = t / 24;
  }
  const int tx = tid & 31, ty = tid >> 5;
  const int c0 = bx * 32, r0 = by * 32;
  for (int i = ty; i < 32; i += 8)
    tile[i][tx] = f2b_hw(in[(size_t)(r0 + i) * C + c0 + tx]);
  __syncthreads();
  for (int i = ty; i < 32; i += 8)
    out[(size_t)(c0 + i) * R + r0 + tx] = tile[tx][i];
}

// ---------- MFMA GEMM, BK=32, double-buffered prefetch (r6, unchanged) ----------
typedef __bf16 bf16x8 __attribute__((ext_vector_type(8)));
typedef float f32x4 __attribute__((ext_vector_type(4)));

template <bool OUTF, int BM>  // BM = M-tile (128 or 64), N-tile fixed 128
__global__ __launch_bounds__(256) void gemm_bt(const ushort_t* __restrict__ A,
                                               const ushort_t* __restrict__ Bt,
                                               const float* __restrict__ bias,
                                               void* __restrict__ Cv,
                                               int M, int N, int K) {
  constexpr int TM = BM / 32;
  __shared__ ushort_t As[2][BM * 32];
  __shared__ ushort_t Bs[2][128 * 32];
  const int tid = threadIdx.x;
  const int m0 = blockIdx.y * BM, n0 = blockIdx.x * 128;
  const int wid = tid >> 6, lane = tid & 63;
  const int quad = lane >> 4, l15 = lane & 15;
  const int wm = (wid >> 1) * (BM / 2), wn = (wid & 1) * 64;
  f32x4 acc[TM][4] = {};

  const int e0 = tid * 8;               // lane-linear 16B chunks
  const int r0s = e0 >> 5, c0s = e0 & 31;
  const int e1 = e0 + 2048;
  const int r1s = e1 >> 5, c1s = e1 & 31;

  const int KS = K >> 5;  // K-steps of 32

#define GSTAGE(ks, bf)                                                              \
  {                                                                                 \
    const int kc = (ks) << 5;                                                       \
    async_cp16(&A[(size_t)(m0 + r0s) * K + kc + c0s], &As[bf][e0]);                 \
    if constexpr (BM == 128)                                                        \
      async_cp16(&A[(size_t)(m0 + r1s) * K + kc + c1s], &As[bf][e1]);               \
    async_cp16(&Bt[(size_t)(n0 + r0s) * K + kc + c0s], &Bs[bf][e0]);                \
    async_cp16(&Bt[(size_t)(n0 + r1s) * K + kc + c1s], &Bs[bf][e1]);                \
  }

  GSTAGE(0, 0);
  for (int ks = 0; ks < KS; ks++) {
    const int pb = ks & 1;
    __syncthreads();  // tile ks staged (barrier drains vmcnt)
    if (ks + 1 < KS) GSTAGE(ks + 1, pb ^ 1);
    bf16x8 af[TM], bfr[4];
#pragma unroll
    for (int t = 0; t < TM; t++)
      af[t] = *(const bf16x8*)&As[pb][(wm + t * 16 + l15) * 32 + quad * 8];
#pragma unroll
    for (int t = 0; t < 4; t++)
      bfr[t] = *(const bf16x8*)&Bs[pb][(wn + t * 16 + l15) * 32 + quad * 8];
#pragma unroll
    for (int tm = 0; tm < TM; tm++)
#pragma unroll
      for (int tn = 0; tn < 4; tn++)
        acc[tm][tn] = __builtin_amdgcn_mfma_f32_16x16x32_bf16(af[tm], bfr[tn], acc[tm][tn], 0, 0, 0);
  }
#undef GSTAGE

#pragma unroll
  for (int tm = 0; tm < TM; tm++) {
    const int row = m0 + wm + tm * 16 + quad * 4;
#pragma unroll
    for (int tn = 0; tn < 4; tn++) {
      const int col = n0 + wn + tn * 16 + l15;
      const float bv = bias[col];
#pragma unroll
      for (int rr = 0; rr < 4; rr++) {
        if constexpr (OUTF)
          ((float*)Cv)[(size_t)(row + rr) * N + col] = acc[tm][tn][rr] + bv;
        else
          ((ushort_t*)Cv)[(size_t)(row + rr) * N + col] = f2b_hw(acc[tm][tn][rr] + bv);
      }
    }
  }
}

// ---------- MFMA flash attention (S^T / O^T form), causal ----------
// 64-q tile per block, 128 threads (2 waves x 32 q via 2 Q-fragments).
// Per-wave compute identical to r6 (verified); only block granularity halves.
// Grid (48 bh, 32 qt), qt = 31-y, monotone big-first: 1536 blocks, 5/CU
// resident (32KB LDS), 256 queued -> queued blocks are the 1-6 iter ones, so
// the static-assignment tail (r6: per-CU 36-66 iters) collapses to ~uniform.
// P in registers + K=32 PV via key-permuted Ksm (r6, conflicts==0):
//   slot p holds true key perm(p)=32*(p>>5)+8*((p>>2)&3)+4*((p>>4)&1)+(p&3);
//   key_true(p+32)=key_true(p)+32, so 128-thread staging = 4 async calls
//   (2 d-halves x 2 slot-groups), same chunk swizzle (tid&3)^((tid>>3)&3).
// V: each thread commits 2 d-groups (vd0, vd0+32); chunk swizzle unchanged
// ((d+32)&7 == d&7 -> offset +32*VSTR). Reads vroff unchanged.
#define VSTR 64

__device__ __forceinline__ void commit_v(ushort_t* __restrict__ vt, const int* __restrict__ offs,
                                         uint4 pV0, uint4 pV1) {
  union { uint32_t u[4]; uint4 v; } a, c;
  a.v = pV0; c.v = pV1;
#pragma unroll
  for (int j = 0; j < 8; j++) {
    uint32_t pk = __builtin_amdgcn_perm(c.u[j >> 1], a.u[j >> 1],
                                        (j & 1) ? 0x07060302u : 0x05040100u);
    *(uint32_t*)&vt[offs[j]] = pk;
  }
}

__global__ __launch_bounds__(128, 2) void attn_mfma_k(const ushort_t* __restrict__ qkv,
                                                      ushort_t* __restrict__ y) {
  __shared__ ushort_t Ksm[2][2][64 * 32];  // [buf][d-half][keyslot*32] 16384 B
  __shared__ ushort_t Vt[2][64 * VSTR];    // [buf][d][key] swizzled    16384 B

  const int qt = 31 - blockIdx.y;          // big tiles first (LPT)
  const int h = blockIdx.x >> 2, b = blockIdx.x & 3;
  const int tid = threadIdx.x;             // 0..127
  const int w = tid >> 6, lane = tid & 63;
  const int quad = lane >> 4, l15 = lane & 15;
  const int nkt = qt + 1;                  // 64-key tiles
  const int qw = qt * 64 + w * 32;         // wave's first q row

  // K staging: slot p = tid>>2 (+32 for group 1); global row = key_true(p);
  // chunk swizzle (tid&3)^((tid>>3)&3) same for both groups. LDS dest
  // lane-linear (rule #21): group g, half h -> Ksm[buf][h][g*1024 + tid*8].
  const int e0 = tid * 8;
  const int p_slot = tid >> 2;
  const int key_true = ((p_slot >> 5) << 5) | (((p_slot >> 2) & 3) << 3) |
                       (((p_slot >> 4) & 1) << 2) | (p_slot & 3);
  const int kchunk = (tid & 3) ^ ((tid >> 3) & 3);
  const ushort_t* kbase = qkv + ((size_t)(b * T_SEQ) + key_true) * C3 + CEMB + h * HDIM + kchunk * 8;
  const int vpair = tid & 31, vd0 = ((tid >> 5) & 3) * 8;  // vd0 in {0,8,16,24}
  const ushort_t* vbase = qkv + ((size_t)(b * T_SEQ) + 2 * vpair) * C3 + 2 * CEMB + h * HDIM + vd0;
  const size_t step = (size_t)64 * C3;
  const size_t krow32 = (size_t)32 * C3;   // key_true(p+32) = key_true(p)+32

  // V-commit offsets: keys {2vpair,2vpair+1}, rows d=vd0+j, chunk (vpair>>2)^j
  int voffw[8];
#pragma unroll
  for (int j = 0; j < 8; j++)
    voffw[j] = (vd0 + j) * VSTR + (((vpair >> 2) ^ j) << 3) + ((vpair & 3) << 1);

  const int sw7 = l15 & 7;
  int koff[4];
#pragma unroll
  for (int m = 0; m < 4; m++)
    koff[m] = (m * 16 + l15) * 32 + ((quad ^ ((l15 >> 1) & 3)) << 3);
  // Vt b128 reads: row nd*16+l15, true keys 32a+quad*8..+7, chunk (4a+quad)^sw7
  int vroff[2][4];
#pragma unroll
  for (int a2 = 0; a2 < 2; a2++)
#pragma unroll
    for (int nd = 0; nd < 4; nd++)
      vroff[a2][nd] = (nd * 16 + l15) * VSTR + (((4 * a2 + quad) ^ sw7) << 3);

  const int qrel0 = w * 32 + l15;  // block-relative q rows (for mask)
  const int qrel1 = qrel0 + 16;

  const float C2 = 0.18033688011112042f;  // 0.125 * log2(e)

  // Q fragments (B-operand): rows qw + qf*16 + l15 = wave's 32 q
  bf16x8 qB[2][2];
#pragma unroll
  for (int qf = 0; qf < 2; qf++)
#pragma unroll
    for (int kb = 0; kb < 2; kb++)
      qB[qf][kb] = *(const bf16x8*)&qkv[((size_t)(b * T_SEQ + qw + qf * 16 + l15)) * C3 +
                                        h * HDIM + kb * 32 + quad * 8];

  f32x4 o2[2][4] = {};  // O^T per frag: [d-sub], row=d(quad*4+r), col=q(l15)
  float m0 = -3e38f, m1 = -3e38f;
  float lq0 = 0.f, lq1 = 0.f;  // per-lane quad-partial row sums

#define KSTAGE(buf)                                          \
  {                                                          \
    async_cp16(kp, &Ksm[buf][0][e0]);                        \
    async_cp16(kp + krow32, &Ksm[buf][0][e0 + 1024]);        \
    async_cp16(kp + 32, &Ksm[buf][1][e0]);                   \
    async_cp16(kp + krow32 + 32, &Ksm[buf][1][e0 + 1024]);   \
  }
#define VLOAD()                                              \
  {                                                          \
    pV0 = *(const uint4*)vp; pV1 = *(const uint4*)(vp + C3); \
    pV0b = *(const uint4*)(vp + 32);                         \
    pV1b = *(const uint4*)(vp + C3 + 32);                    \
  }
#define VCOMMIT(buf)                                         \
  {                                                          \
    commit_v(Vt[buf], voffw, pV0, pV1);                      \
    commit_v(&Vt[buf][32 * VSTR], voffw, pV0b, pV1b);        \
  }

  // ---- prologue: stage tile 0, prefetch V tile 1 ----
  const ushort_t* kp = kbase;
  const ushort_t* vp = vbase;
  uint4 pV0, pV1, pV0b, pV1b;
  VLOAD();
  KSTAGE(0);
  VCOMMIT(0);
  vp += step;
  VLOAD();

  for (int kt = 0; kt < nkt; ++kt) {
    __syncthreads();  // tile kt staged (barrier drains vmcnt + lgkmcnt)
    // ---- stage tile kt+1 into the other buffer (overlaps compute) ----
    if (kt + 1 < nkt) {
      const int nb = (kt + 1) & 1;
      kp += step;
      KSTAGE(nb);
      VCOMMIT(nb);
      if (kt + 2 < nkt) {
        vp += step;
        VLOAD();
      }
    }
    const int cb = kt & 1;

    // ---- S^T = K*Q^T for both q-frags (kA reused) ----
    bf16x8 kA[4][2];
#pragma unroll
    for (int m = 0; m < 4; m++) {
      kA[m][0] = *(const bf16x8*)&Ksm[cb][0][koff[m]];
      kA[m][1] = *(const bf16x8*)&Ksm[cb][1][koff[m]];
    }
    f32x4 st0[4] = {}, st1[4] = {};
#pragma unroll
    for (int m = 0; m < 4; m++) {
      st0[m] = __builtin_amdgcn_mfma_f32_16x16x32_bf16(kA[m][0], qB[0][0], st0[m], 0, 0, 0);
      st0[m] = __builtin_amdgcn_mfma_f32_16x16x32_bf16(kA[m][1], qB[0][1], st0[m], 0, 0, 0);
      st1[m] = __builtin_amdgcn_mfma_f32_16x16x32_bf16(kA[m][0], qB[1][0], st1[m], 0, 0, 0);
      st1[m] = __builtin_amdgcn_mfma_f32_16x16x32_bf16(kA[m][1], qB[1][1], st1[m], 0, 0, 0);
    }

    // ---- causal mask (permuted keys): diagonal tile only ----
    if (kt == nkt - 1) {
      const int kb0 = quad * 8;  // block-relative: kt == qt
#pragma unroll
      for (int m = 0; m < 4; m++) {
        const int bm = kb0 + ((m >> 1) << 5) + ((m & 1) << 2);
#pragma unroll
        for (int r = 0; r < 4; r++) {
          const int kr = bm + r;
          if (kr > qrel0) st0[m][r] = -3e38f;
          if (kr > qrel1) st1[m][r] = -3e38f;
        }
      }
    }

    // ---- online softmax: defer-max (T13); no cross-lane in common path ----
    f32x4 mq0, mq1;
#pragma unroll
    for (int r = 0; r < 4; r++) {
      mq0[r] = fmaxf(fmaxf(st0[0][r], st0[1][r]), fmaxf(st0[2][r], st0[3][r]));
      mq1[r] = fmaxf(fmaxf(st1[0][r], st1[1][r]), fmaxf(st1[2][r], st1[3][r]));
    }
    const float mx0 = fmaxf(fmaxf(mq0[0], mq0[1]), fmaxf(mq0[2], mq0[3]));
    const float mx1 = fmaxf(fmaxf(mq1[0], mq1[1]), fmaxf(mq1[2], mq1[3]));

    float al0 = 1.f, al1 = 1.f;
    const bool viol = (mx0 - m0 > 22.18f) || (mx1 - m1 > 22.18f);
    if (__any(viol)) {
      float a = fmaxf(mx0, __shfl_xor(mx0, 16, 64));
      a = fmaxf(a, __shfl_xor(a, 32, 64));
      float bm = fmaxf(mx1, __shfl_xor(mx1, 16, 64));
      bm = fmaxf(bm, __shfl_xor(bm, 32, 64));
      const float n0 = fmaxf(m0, a), n1 = fmaxf(m1, bm);
      al0 = exp2f((m0 - n0) * C2);
      al1 = exp2f((m1 - n1) * C2);
      m0 = n0; m1 = n1;
#pragma unroll
      for (int nd = 0; nd < 4; nd++)
#pragma unroll
        for (int r = 0; r < 4; r++) {
          o2[0][nd][r] *= al0;
          o2[1][nd][r] *= al1;
        }
    }
    const float mnc0 = m0 * C2, mnc1 = m1 * C2;
#pragma unroll
    for (int m = 0; m < 4; m++)
#pragma unroll
      for (int r = 0; r < 4; r++) {
        st0[m][r] = exp2f(fmaf(st0[m][r], C2, -mnc0));
        st1[m][r] = exp2f(fmaf(st1[m][r], C2, -mnc1));
      }
    f32x4 s40, s41;
#pragma unroll
    for (int r = 0; r < 4; r++) {
      s40[r] = (st0[0][r] + st0[1][r]) + (st0[2][r] + st0[3][r]);
      s41[r] = (st1[0][r] + st1[1][r]) + (st1[2][r] + st1[3][r]);
    }
    lq0 = fmaf(lq0, al0, (s40[0] + s40[1]) + (s40[2] + s40[3]));
    lq1 = fmaf(lq1, al1, (s41[0] + s41[1]) + (s41[2] + s41[3]));

    // ---- P -> 16x16x32 B-fragments in registers (true keys 32a+quad*8+j) ----
    bf16x8 pf0[2], pf1[2];
#pragma unroll
    for (int a2 = 0; a2 < 2; a2++) {
      union { uint32_t u[4]; bf16x8 v; } pa, pb;
      pa.u[0] = pkbf16(st0[2 * a2][0], st0[2 * a2][1]);
      pa.u[1] = pkbf16(st0[2 * a2][2], st0[2 * a2][3]);
      pa.u[2] = pkbf16(st0[2 * a2 + 1][0], st0[2 * a2 + 1][1]);
      pa.u[3] = pkbf16(st0[2 * a2 + 1][2], st0[2 * a2 + 1][3]);
      pb.u[0] = pkbf16(st1[2 * a2][0], st1[2 * a2][1]);
      pb.u[1] = pkbf16(st1[2 * a2][2], st1[2 * a2][3]);
      pb.u[2] = pkbf16(st1[2 * a2 + 1][0], st1[2 * a2 + 1][1]);
      pb.u[3] = pkbf16(st1[2 * a2 + 1][2], st1[2 * a2 + 1][3]);
      pf0[a2] = pa.v; pf1[a2] = pb.v;
    }

    // ---- O^T += V^T * P^T  (16x16x32; V b128 reused across q-frags) ----
#pragma unroll
    for (int a2 = 0; a2 < 2; a2++)
#pragma unroll
      for (int nd = 0; nd < 4; nd++) {
        const bf16x8 vv = *(const bf16x8*)&Vt[cb][vroff[a2][nd]];
        o2[0][nd] = __builtin_amdgcn_mfma_f32_16x16x32_bf16(vv, pf0[a2], o2[0][nd], 0, 0, 0);
        o2[1][nd] = __builtin_amdgcn_mfma_f32_16x16x32_bf16(vv, pf1[a2], o2[1][nd], 0, 0, 0);
      }
  }
#undef KSTAGE
#undef VLOAD
#undef VCOMMIT

  // ---- epilogue: cross-quad l reduce (deferred), then y stores ----
  {
    float lt0 = lq0 + __shfl_xor(lq0, 16, 64);
    lt0 += __shfl_xor(lt0, 32, 64);
    float lt1 = lq1 + __shfl_xor(lq1, 16, 64);
    lt1 += __shfl_xor(lt1, 32, 64);
    const float inv0 = 1.0f / lt0, inv1 = 1.0f / lt1;
#pragma unroll
    for (int qf = 0; qf < 2; qf++) {
      const float inv = qf ? inv1 : inv0;
      const int qg = qw + qf * 16 + l15;
      ushort_t* yp = y + ((size_t)(b * T_SEQ + qg)) * CEMB + h * HDIM + quad * 4;
#pragma unroll
      for (int nd = 0; nd < 4; nd++) {
        uint2 pk;
        pk.x = pkbf16(o2[qf][nd][0] * inv, o2[qf][nd][1] * inv);
        pk.y = pkbf16(o2[qf][nd][2] * inv, o2[qf][nd][3] * inv);
        *(uint2*)(yp + nd * 16) = pk;
      }
    }
  }
}

// ---------- launcher ----------
extern "C" void kernel_launch(void* const* d_in, const int* in_sizes, int n_in,
                              void* d_out, int out_size, void* d_ws, size_t ws_size,
                              hipStream_t stream) {
  const float* x      = (const float*)d_in[0];  // [4,2048,768] fp32
  const float* w_attn = (const float*)d_in[1];  // [768,2304]
  const float* b_attn = (const float*)d_in[2];  // [2304]
  const float* w_proj = (const float*)d_in[3];  // [768,768]
  const float* b_proj = (const float*)d_in[4];  // [768]
  float* out = (float*)d_out;                   // [4,2048,768] fp32

  char* ws = (char*)d_ws;
  ushort_t* qkv = (ushort_t*)ws;                          // 8192*2304 bf16
  ushort_t* y   = qkv + (size_t)8192 * 2304;              // 8192*768
  ushort_t* xb  = y + (size_t)8192 * 768;                 // 8192*768 bf16 x
  ushort_t* wT  = xb + (size_t)8192 * 768;                // 2304*768 (w_attn^T)
  ushort_t* wpT = wT + (size_t)2304 * 768;                // 768*768  (w_proj^T)

  // fused prep: cvt x + transpose both weights
  prep_k<<<5376, 256, 0, stream>>>(x, xb, w_attn, wT, w_proj, wpT);

  // qkv = x @ w_attn + b_attn   (M=8192, N=2304, K=768), bf16 out
  gemm_bt<false, 128><<<dim3(C3 / 128, 8192 / 128), 256, 0, stream>>>(xb, wT, b_attn, qkv, 8192, C3, CEMB);

  // MFMA flash attention -> y [B,T,C] bf16; 64-q blocks, 128 thr, big-first
  attn_mfma_k<<<dim3(48, 32), 128, 0, stream>>>(qkv, y);

  // out = y @ w_proj + b_proj   (M=8192, N=768, K=768), fp32 out
  gemm_bt<true, 64><<<dim3(CEMB / 128, 8192 / 64), 256, 0, stream>>>(y, wpT, b_proj, out, 8192, CEMB, CEMB);
}

// Round 8
// 215.408 us; speedup vs baseline: 1.1107x; 1.1107x over previous
//
#include <hip/hip_runtime.h>
#include <stdint.h>

typedef unsigned short ushort_t;

#define T_SEQ 2048
#define BATCH 4
#define NHEAD 12
#define CEMB 768
#define HDIM 64
#define C3 2304

// ---------- bf16 helpers (HW convert, RNE) ----------
__device__ __forceinline__ ushort_t f2b_hw(float f) {
  union { __bf16 h; ushort_t u; } p;
  p.h = (__bf16)f;
  return p.u;
}
__device__ __forceinline__ uint32_t pkbf16(float lo, float hi) {
  union { __bf16 h[2]; uint32_t u; } p;
  p.h[0] = (__bf16)lo; p.h[1] = (__bf16)hi;
  return p.u;
}

// ---------- async global->LDS 16B ----------
typedef __attribute__((address_space(3))) unsigned int lds_u32_t;
typedef const __attribute__((address_space(1))) unsigned int glb_u32_t;
__device__ __forceinline__ void async_cp16(const void* g, void* l) {
  __builtin_amdgcn_global_load_lds((glb_u32_t*)g, (lds_u32_t*)l, 16, 0, 0);
}

// ---------- fused prep: cvt x -> bf16; transpose+cvt both weights ----------
__global__ __launch_bounds__(256) void prep_k(const float* __restrict__ x, ushort_t* __restrict__ xb,
                                              const float* __restrict__ wa, ushort_t* __restrict__ wT,
                                              const float* __restrict__ wp, ushort_t* __restrict__ wpT) {
  const int blk = blockIdx.x;
  const int tid = threadIdx.x;
  if (blk < 3072) {
    const int i = blk * 256 + tid;
    float4 a = ((const float4*)x)[2 * i];
    float4 b = ((const float4*)x)[2 * i + 1];
    uint4 v;
    v.x = pkbf16(a.x, a.y); v.y = pkbf16(a.z, a.w);
    v.z = pkbf16(b.x, b.y); v.w = pkbf16(b.z, b.w);
    ((uint4*)xb)[i] = v;
    return;
  }
  __shared__ ushort_t tile[32][33];
  const float* in; ushort_t* out; int R, C, bx, by;
  if (blk < 4800) {
    const int t = blk - 3072;
    in = wa; out = wT; R = CEMB; C = C3;
    bx = t % 72; by = t / 72;
  } else {
    const int t = blk - 4800;
    in = wp; out = wpT; R = CEMB; C = CEMB;
    bx = t % 24; by = t / 24;
  }
  const int tx = tid & 31, ty = tid >> 5;
  const int c0 = bx * 32, r0 = by * 32;
  for (int i = ty; i < 32; i += 8)
    tile[i][tx] = f2b_hw(in[(size_t)(r0 + i) * C + c0 + tx]);
  __syncthreads();
  for (int i = ty; i < 32; i += 8)
    out[(size_t)(c0 + i) * R + r0 + tx] = tile[tx][i];
}

// ---------- MFMA GEMM, BK=32, double-buffered prefetch (r6, unchanged) ----------
typedef __bf16 bf16x8 __attribute__((ext_vector_type(8)));
typedef float f32x4 __attribute__((ext_vector_type(4)));

template <bool OUTF, int BM>  // BM = M-tile (128 or 64), N-tile fixed 128
__global__ __launch_bounds__(256) void gemm_bt(const ushort_t* __restrict__ A,
                                               const ushort_t* __restrict__ Bt,
                                               const float* __restrict__ bias,
                                               void* __restrict__ Cv,
                                               int M, int N, int K) {
  constexpr int TM = BM / 32;
  __shared__ ushort_t As[2][BM * 32];
  __shared__ ushort_t Bs[2][128 * 32];
  const int tid = threadIdx.x;
  const int m0 = blockIdx.y * BM, n0 = blockIdx.x * 128;
  const int wid = tid >> 6, lane = tid & 63;
  const int quad = lane >> 4, l15 = lane & 15;
  const int wm = (wid >> 1) * (BM / 2), wn = (wid & 1) * 64;
  f32x4 acc[TM][4] = {};

  const int e0 = tid * 8;               // lane-linear 16B chunks
  const int r0s = e0 >> 5, c0s = e0 & 31;
  const int e1 = e0 + 2048;
  const int r1s = e1 >> 5, c1s = e1 & 31;

  const int KS = K >> 5;  // K-steps of 32

#define GSTAGE(ks, bf)                                                              \
  {                                                                                 \
    const int kc = (ks) << 5;                                                       \
    async_cp16(&A[(size_t)(m0 + r0s) * K + kc + c0s], &As[bf][e0]);                 \
    if constexpr (BM == 128)                                                        \
      async_cp16(&A[(size_t)(m0 + r1s) * K + kc + c1s], &As[bf][e1]);               \
    async_cp16(&Bt[(size_t)(n0 + r0s) * K + kc + c0s], &Bs[bf][e0]);                \
    async_cp16(&Bt[(size_t)(n0 + r1s) * K + kc + c1s], &Bs[bf][e1]);                \
  }

  GSTAGE(0, 0);
  for (int ks = 0; ks < KS; ks++) {
    const int pb = ks & 1;
    __syncthreads();  // tile ks staged (barrier drains vmcnt)
    if (ks + 1 < KS) GSTAGE(ks + 1, pb ^ 1);
    bf16x8 af[TM], bfr[4];
#pragma unroll
    for (int t = 0; t < TM; t++)
      af[t] = *(const bf16x8*)&As[pb][(wm + t * 16 + l15) * 32 + quad * 8];
#pragma unroll
    for (int t = 0; t < 4; t++)
      bfr[t] = *(const bf16x8*)&Bs[pb][(wn + t * 16 + l15) * 32 + quad * 8];
#pragma unroll
    for (int tm = 0; tm < TM; tm++)
#pragma unroll
      for (int tn = 0; tn < 4; tn++)
        acc[tm][tn] = __builtin_amdgcn_mfma_f32_16x16x32_bf16(af[tm], bfr[tn], acc[tm][tn], 0, 0, 0);
  }
#undef GSTAGE

#pragma unroll
  for (int tm = 0; tm < TM; tm++) {
    const int row = m0 + wm + tm * 16 + quad * 4;
#pragma unroll
    for (int tn = 0; tn < 4; tn++) {
      const int col = n0 + wn + tn * 16 + l15;
      const float bv = bias[col];
#pragma unroll
      for (int rr = 0; rr < 4; rr++) {
        if constexpr (OUTF)
          ((float*)Cv)[(size_t)(row + rr) * N + col] = acc[tm][tn][rr] + bv;
        else
          ((ushort_t*)Cv)[(size_t)(row + rr) * N + col] = f2b_hw(acc[tm][tn][rr] + bv);
      }
    }
  }
}

// ---------- MFMA flash attention (S^T / O^T form), causal ----------
// 64-q tile per block, 256 threads: 4 waves x 16 q (single Q-fragment).
// TLP model (r6/r7 retrodiction): wall = max(chain/waves_per_SIMD, DS floor).
// r6: 3 waves/SIMD -> 75us; r7: 2.5 -> 95us. This config: 32KB LDS, 1536
// blocks, 5 blocks/CU resident = 5 waves/SIMD (launch_bounds(256,5), VGPR
// cap 102, est ~60 -> no spill). LPT big-first: 1280 resident + 256 smallest
// queued -> tail collapses.
// P in registers + K=32 PV via key-permuted Ksm (r6-verified, conflicts==0):
//   slot p holds true key perm(p)=32*(p>>5)+8*((p>>2)&3)+4*((p>>4)&1)+(p&3);
//   S^T slices m=2a,2a+1 give lane (quad,l15) true keys 32a+quad*8+{0..7} ->
//   packed st regs form a 16x16x32 B-fragment; V^T A-frag is one b128 read.
// Swizzles: Ksm src-side chunk ^= (p>>1)&3 (rule #21); Vt commit/read pair
// verified r2/r3/r6.
#define VSTR 64

__device__ __forceinline__ void commit_v(ushort_t* __restrict__ vt, const int* __restrict__ offs,
                                         uint4 pV0, uint4 pV1) {
  union { uint32_t u[4]; uint4 v; } a, c;
  a.v = pV0; c.v = pV1;
#pragma unroll
  for (int j = 0; j < 8; j++) {
    uint32_t pk = __builtin_amdgcn_perm(c.u[j >> 1], a.u[j >> 1],
                                        (j & 1) ? 0x07060302u : 0x05040100u);
    *(uint32_t*)&vt[offs[j]] = pk;
  }
}

__global__ __launch_bounds__(256, 5) void attn_mfma_k(const ushort_t* __restrict__ qkv,
                                                      ushort_t* __restrict__ y) {
  __shared__ ushort_t Ksm[2][2][64 * 32];  // [buf][d-half][keyslot*32] 16384 B
  __shared__ ushort_t Vt[2][64 * VSTR];    // [buf][d][key] swizzled    16384 B

  const int qt = 31 - blockIdx.y;          // big tiles first (LPT)
  const int h = blockIdx.x >> 2, b = blockIdx.x & 3;
  const int tid = threadIdx.x;
  const int w = tid >> 6, lane = tid & 63;
  const int quad = lane >> 4, l15 = lane & 15;
  const int nkt = qt + 1;                  // 64-key tiles
  const int qw = qt * 64 + w * 16;         // wave's first q row

  // K staging (identical to r6): lane stages 16B chunk of key-slot p=tid>>2;
  // global source row = perm(p); chunk swizzle (tid&3)^((p>>1)&3); LDS dest
  // lane-linear (rule #21).
  const int e0 = tid * 8;
  const int p_slot = tid >> 2;
  const int key_true = ((p_slot >> 5) << 5) | (((p_slot >> 2) & 3) << 3) |
                       (((p_slot >> 4) & 1) << 2) | (p_slot & 3);
  const int kchunk = (tid & 3) ^ ((p_slot >> 1) & 3);
  const ushort_t* kbase = qkv + ((size_t)(b * T_SEQ) + key_true) * C3 + CEMB + h * HDIM + kchunk * 8;
  const int vpair = tid & 31, vd0 = (tid >> 5) * 8;
  const ushort_t* vbase = qkv + ((size_t)(b * T_SEQ) + 2 * vpair) * C3 + 2 * CEMB + h * HDIM + vd0;
  const size_t step = (size_t)64 * C3;

  // V-commit offsets (verified): keys {2vpair,2vpair+1}, rows d=vd0+j,
  // chunk (vpair>>2)^(d&7)
  int voffw[8];
#pragma unroll
  for (int j = 0; j < 8; j++)
    voffw[j] = (vd0 + j) * VSTR + (((vpair >> 2) ^ j) << 3) + ((vpair & 3) << 1);

  const int sw7 = l15 & 7;
  int koff[4];
#pragma unroll
  for (int m = 0; m < 4; m++)
    koff[m] = (m * 16 + l15) * 32 + ((quad ^ ((l15 >> 1) & 3)) << 3);
  // Vt b128 reads: row nd*16+l15, true keys 32a+quad*8..+7, chunk (4a+quad)^sw7
  int vroff[2][4];
#pragma unroll
  for (int a2 = 0; a2 < 2; a2++)
#pragma unroll
    for (int nd = 0; nd < 4; nd++)
      vroff[a2][nd] = (nd * 16 + l15) * VSTR + (((4 * a2 + quad) ^ sw7) << 3);

  const int qrel = w * 16 + l15;  // block-relative q row (for mask)

  const float C2 = 0.18033688011112042f;  // 0.125 * log2(e)

  // Q fragment (B-operand): rows qw + l15 = wave's 16 q
  bf16x8 qB[2];
#pragma unroll
  for (int kb = 0; kb < 2; kb++)
    qB[kb] = *(const bf16x8*)&qkv[((size_t)(b * T_SEQ + qw + l15)) * C3 +
                                  h * HDIM + kb * 32 + quad * 8];

  f32x4 o2[4] = {};  // O^T: [d-sub], row=d(quad*4+r), col=q(l15)
  float m0 = -3e38f;
  float lq0 = 0.f;   // per-lane quad-partial row sums (deferred reduce)

  // ---- prologue: stage tile 0, prefetch V tile 1 ----
  const ushort_t* kp = kbase;
  const ushort_t* vp = vbase;
  uint4 pV0 = *(const uint4*)vp, pV1 = *(const uint4*)(vp + C3);
  async_cp16(kp, &Ksm[0][0][e0]);
  async_cp16(kp + 32, &Ksm[0][1][e0]);
  commit_v(Vt[0], voffw, pV0, pV1);
  vp += step;
  pV0 = *(const uint4*)vp; pV1 = *(const uint4*)(vp + C3);

  for (int kt = 0; kt < nkt; ++kt) {
    __syncthreads();  // tile kt staged (barrier drains vmcnt + lgkmcnt)
    // ---- stage tile kt+1 into the other buffer (overlaps compute) ----
    if (kt + 1 < nkt) {
      const int nb = (kt + 1) & 1;
      kp += step;
      async_cp16(kp, &Ksm[nb][0][e0]);
      async_cp16(kp + 32, &Ksm[nb][1][e0]);
      commit_v(Vt[nb], voffw, pV0, pV1);
      if (kt + 2 < nkt) {
        vp += step;
        pV0 = *(const uint4*)vp; pV1 = *(const uint4*)(vp + C3);
      }
    }
    const int cb = kt & 1;

    // ---- S^T = K*Q^T ----
    bf16x8 kA[4][2];
#pragma unroll
    for (int m = 0; m < 4; m++) {
      kA[m][0] = *(const bf16x8*)&Ksm[cb][0][koff[m]];
      kA[m][1] = *(const bf16x8*)&Ksm[cb][1][koff[m]];
    }
    f32x4 st0[4] = {};
#pragma unroll
    for (int m = 0; m < 4; m++) {
      st0[m] = __builtin_amdgcn_mfma_f32_16x16x32_bf16(kA[m][0], qB[0], st0[m], 0, 0, 0);
      st0[m] = __builtin_amdgcn_mfma_f32_16x16x32_bf16(kA[m][1], qB[1], st0[m], 0, 0, 0);
    }

    // ---- causal mask (permuted keys): diagonal tile only ----
    if (kt == nkt - 1) {
      const int kb0 = quad * 8;
#pragma unroll
      for (int m = 0; m < 4; m++) {
        const int bm = kb0 + ((m >> 1) << 5) + ((m & 1) << 2);
#pragma unroll
        for (int r = 0; r < 4; r++)
          if (bm + r > qrel) st0[m][r] = -3e38f;
      }
    }

    // ---- online softmax: defer-max (T13); no cross-lane in common path ----
    f32x4 mq0;
#pragma unroll
    for (int r = 0; r < 4; r++)
      mq0[r] = fmaxf(fmaxf(st0[0][r], st0[1][r]), fmaxf(st0[2][r], st0[3][r]));
    const float mx0 = fmaxf(fmaxf(mq0[0], mq0[1]), fmaxf(mq0[2], mq0[3]));

    float al0 = 1.f;
    if (__any(mx0 - m0 > 22.18f)) {
      float a = fmaxf(mx0, __shfl_xor(mx0, 16, 64));
      a = fmaxf(a, __shfl_xor(a, 32, 64));
      const float n0 = fmaxf(m0, a);
      al0 = exp2f((m0 - n0) * C2);
      m0 = n0;
#pragma unroll
      for (int nd = 0; nd < 4; nd++)
#pragma unroll
        for (int r = 0; r < 4; r++) o2[nd][r] *= al0;
    }
    const float mnc0 = m0 * C2;
#pragma unroll
    for (int m = 0; m < 4; m++)
#pragma unroll
      for (int r = 0; r < 4; r++)
        st0[m][r] = exp2f(fmaf(st0[m][r], C2, -mnc0));
    f32x4 s40;
#pragma unroll
    for (int r = 0; r < 4; r++)
      s40[r] = (st0[0][r] + st0[1][r]) + (st0[2][r] + st0[3][r]);
    lq0 = fmaf(lq0, al0, (s40[0] + s40[1]) + (s40[2] + s40[3]));

    // ---- P -> 16x16x32 B-fragments in registers (true keys 32a+quad*8+j) ----
    bf16x8 pf0[2];
#pragma unroll
    for (int a2 = 0; a2 < 2; a2++) {
      union { uint32_t u[4]; bf16x8 v; } pa;
      pa.u[0] = pkbf16(st0[2 * a2][0], st0[2 * a2][1]);
      pa.u[1] = pkbf16(st0[2 * a2][2], st0[2 * a2][3]);
      pa.u[2] = pkbf16(st0[2 * a2 + 1][0], st0[2 * a2 + 1][1]);
      pa.u[3] = pkbf16(st0[2 * a2 + 1][2], st0[2 * a2 + 1][3]);
      pf0[a2] = pa.v;
    }

    // ---- O^T += V^T * P^T  (16x16x32) ----
#pragma unroll
    for (int a2 = 0; a2 < 2; a2++)
#pragma unroll
      for (int nd = 0; nd < 4; nd++) {
        const bf16x8 vv = *(const bf16x8*)&Vt[cb][vroff[a2][nd]];
        o2[nd] = __builtin_amdgcn_mfma_f32_16x16x32_bf16(vv, pf0[a2], o2[nd], 0, 0, 0);
      }
  }

  // ---- epilogue: cross-quad l reduce (deferred), then y stores ----
  {
    float lt0 = lq0 + __shfl_xor(lq0, 16, 64);
    lt0 += __shfl_xor(lt0, 32, 64);
    const float inv = 1.0f / lt0;
    const int qg = qw + l15;
    ushort_t* yp = y + ((size_t)(b * T_SEQ + qg)) * CEMB + h * HDIM + quad * 4;
#pragma unroll
    for (int nd = 0; nd < 4; nd++) {
      uint2 pk;
      pk.x = pkbf16(o2[nd][0] * inv, o2[nd][1] * inv);
      pk.y = pkbf16(o2[nd][2] * inv, o2[nd][3] * inv);
      *(uint2*)(yp + nd * 16) = pk;
    }
  }
}

// ---------- launcher ----------
extern "C" void kernel_launch(void* const* d_in, const int* in_sizes, int n_in,
                              void* d_out, int out_size, void* d_ws, size_t ws_size,
                              hipStream_t stream) {
  const float* x      = (const float*)d_in[0];  // [4,2048,768] fp32
  const float* w_attn = (const float*)d_in[1];  // [768,2304]
  const float* b_attn = (const float*)d_in[2];  // [2304]
  const float* w_proj = (const float*)d_in[3];  // [768,768]
  const float* b_proj = (const float*)d_in[4];  // [768]
  float* out = (float*)d_out;                   // [4,2048,768] fp32

  char* ws = (char*)d_ws;
  ushort_t* qkv = (ushort_t*)ws;                          // 8192*2304 bf16
  ushort_t* y   = qkv + (size_t)8192 * 2304;              // 8192*768
  ushort_t* xb  = y + (size_t)8192 * 768;                 // 8192*768 bf16 x
  ushort_t* wT  = xb + (size_t)8192 * 768;                // 2304*768 (w_attn^T)
  ushort_t* wpT = wT + (size_t)2304 * 768;                // 768*768  (w_proj^T)

  // fused prep: cvt x + transpose both weights
  prep_k<<<5376, 256, 0, stream>>>(x, xb, w_attn, wT, w_proj, wpT);

  // qkv = x @ w_attn + b_attn   (M=8192, N=2304, K=768), bf16 out
  gemm_bt<false, 128><<<dim3(C3 / 128, 8192 / 128), 256, 0, stream>>>(xb, wT, b_attn, qkv, 8192, C3, CEMB);

  // MFMA flash attention -> y [B,T,C] bf16; 64-q blocks, 256 thr, big-first
  attn_mfma_k<<<dim3(48, 32), 256, 0, stream>>>(qkv, y);

  // out = y @ w_proj + b_proj   (M=8192, N=768, K=768), fp32 out
  gemm_bt<true, 64><<<dim3(CEMB / 128, 8192 / 64), 256, 0, stream>>>(y, wpT, b_proj, out, 8192, CEMB, CEMB);
}